// Round 9
// baseline (872.897 us; speedup 1.0000x reference)
//
#include <hip/hip_runtime.h>
#include <hip/hip_bf16.h>
#include <math.h>

#define NN 100000
#define F_IN 128
#define NHEAD 2
#define NC 32
#define HC 64
#define NE 3200000
#define NG 64
#define NEG_SLOPE 0.2f

#define BSHIFT 8
#define NBUCK ((NN + (1 << BSHIFT) - 1) >> BSHIFT)   // 391
#define BCAP 10240   // mean 8192 edges/bucket, huge headroom

// ---------------- CSR build ----------------
// Pass A: bin edges by dst-bucket into fixed-capacity staging, 4B packed entries.
__global__ __launch_bounds__(256) void k_binA(const int* __restrict__ ei,
                                              int* __restrict__ gcnt,
                                              unsigned* __restrict__ stg) {
    __shared__ int lcnt[NBUCK];
    __shared__ int lbase[NBUCK];
    const int tid = threadIdx.x;
    const int base = blockIdx.x * 4096;
    for (int i = tid; i < NBUCK; i += 256) lcnt[i] = 0;
    __syncthreads();
    unsigned e[16];
    int bk[16], off[16];
#pragma unroll
    for (int i = 0; i < 16; ++i) {
        int j = base + i * 256 + tid;
        bk[i] = -1;
        if (j < NE) {
            unsigned s = (unsigned)ei[j];
            unsigned d = (unsigned)ei[NE + j];
            int b = (int)(d >> BSHIFT);
            bk[i] = b;
            e[i] = ((d & ((1u << BSHIFT) - 1)) << 17) | s;
            off[i] = atomicAdd(&lcnt[b], 1);
        }
    }
    __syncthreads();
    for (int i = tid; i < NBUCK; i += 256) {
        int c = lcnt[i];
        lbase[i] = c ? atomicAdd(&gcnt[i], c) : 0;
    }
    __syncthreads();
#pragma unroll
    for (int i = 0; i < 16; ++i)
        if (bk[i] >= 0)
            stg[(size_t)bk[i] * BCAP + lbase[bk[i]] + off[i]] = e[i];
}

// Pass B: one block per bucket; self-computes its prefix base from gcnt,
// sorts bucket's edges by dst in LDS, emits rp, streams col contiguously.
__global__ __launch_bounds__(256) void k_binB(const unsigned* __restrict__ stg,
                                              const int* __restrict__ gcnt,
                                              int* __restrict__ rp,
                                              int* __restrict__ col) {
    __shared__ int cnt[256];
    __shared__ int off[256];
    __shared__ int buf[BCAP];
    __shared__ int wsum[4];
    const int b = blockIdx.x, t = threadIdx.x;
    const int len = gcnt[b];
    const unsigned* sb = stg + (size_t)b * BCAP;

    // lo = exclusive prefix sum of gcnt over buckets < b
    int part = 0;
    for (int j = t; j < b; j += 256) part += gcnt[j];
#pragma unroll
    for (int mk = 32; mk; mk >>= 1) part += __shfl_xor(part, mk, 64);
    if ((t & 63) == 0) wsum[t >> 6] = part;
    cnt[t] = 0;
    __syncthreads();
    const int lo = wsum[0] + wsum[1] + wsum[2] + wsum[3];

    for (int j = t; j < len; j += 256) atomicAdd(&cnt[sb[j] >> 17], 1);
    __syncthreads();
    int v = cnt[t];
    off[t] = v;
    __syncthreads();
    for (int d = 1; d < 256; d <<= 1) {
        int u = (t >= d) ? off[t - d] : 0;
        __syncthreads();
        off[t] += u;
        __syncthreads();
    }
    int excl = off[t] - v;
    int node = (b << BSHIFT) + t;
    if (node <= NN) rp[node] = lo + excl;
    __syncthreads();
    off[t] = excl;
    __syncthreads();
    for (int j = t; j < len; j += 256) {
        unsigned e = sb[j];
        int slot = atomicAdd(&off[e >> 17], 1);
        buf[slot] = (int)(e & 0x1FFFFu);
    }
    __syncthreads();
    for (int j = t; j < len; j += 256) col[lo + j] = buf[j];
}

// ---------------- GEMM + attention-coefficient epilogue ----------------
// W in VGPRs (lane = output col). X row address is wave-uniform: forced scalar
// via readfirstlane -> s_load broadcast, no LDS, no barrier.
template <int K>
__global__ __launch_bounds__(256) void k_gemm(const float* __restrict__ xin,
                                              const float* __restrict__ W,
                                              const float* __restrict__ a_src,
                                              const float* __restrict__ a_dst,
                                              float* __restrict__ h,
                                              float* __restrict__ as_out,
                                              float* __restrict__ ad_out) {
    constexpr int KQ = K / 4;
    int tid = threadIdx.x, lane = tid & 63;
    int wid = blockIdx.x * 4 + (tid >> 6);
    const int nwaves = gridDim.x * 4;
    float4 wreg[KQ];
    const float4* W4 = (const float4*)W;
#pragma unroll
    for (int q = 0; q < KQ; ++q) wreg[q] = W4[lane * KQ + q];
    int head = lane >> 5, c = lane & 31;
    float asw = a_src[head * 32 + c];
    float adw = a_dst[head * 32 + c];

    for (int n = wid; n < NN; n += nwaves) {
        int nu = __builtin_amdgcn_readfirstlane(n);
        const float4* xr = (const float4*)(xin + (size_t)nu * K);
        float acc0 = 0.f, acc1 = 0.f;
#pragma unroll
        for (int q = 0; q < KQ; q += 2) {
            float4 xv0 = xr[q];
            float4 xv1 = xr[q + 1];
            acc0 = fmaf(xv0.x, wreg[q].x, acc0);
            acc0 = fmaf(xv0.y, wreg[q].y, acc0);
            acc0 = fmaf(xv0.z, wreg[q].z, acc0);
            acc0 = fmaf(xv0.w, wreg[q].w, acc0);
            acc1 = fmaf(xv1.x, wreg[q + 1].x, acc1);
            acc1 = fmaf(xv1.y, wreg[q + 1].y, acc1);
            acc1 = fmaf(xv1.z, wreg[q + 1].z, acc1);
            acc1 = fmaf(xv1.w, wreg[q + 1].w, acc1);
        }
        float acc = acc0 + acc1;
        h[(size_t)n * 64 + lane] = acc;
        float ts = acc * asw;
        float td = acc * adw;
#pragma unroll
        for (int m = 1; m < 32; m <<= 1) {
            ts += __shfl_xor(ts, m, 64);
            td += __shfl_xor(td, m, 64);
        }
        if (c == 0) {
            as_out[n * 2 + head] = ts;
            ad_out[n * 2 + head] = td;
        }
    }
}

// ---------------- per-destination softmax aggregation ----------------
// (unchanged from round 8 — bandwidth-bound at ~117us, clean A/B for gemm)
__global__ __launch_bounds__(256) void k_agg(const float* __restrict__ h,
                                             const float* __restrict__ as,
                                             const float* __restrict__ ad,
                                             const int* __restrict__ rp,
                                             const int* __restrict__ col,
                                             const float* __restrict__ bias,
                                             float* __restrict__ xout) {
    __shared__ float4 pbuf[4][64];
    int wave = threadIdx.x >> 6, lane = threadIdx.x & 63;
    int n = blockIdx.x * 4 + wave;
    if (n >= NN) return;
    int s0 = rp[n], s1 = rp[n + 1];
    float2 adv = ((const float2*)ad)[n];

    int f4 = lane & 15;
    int q = lane >> 4;
    int headq = f4 >> 3;
    const char* hbase = (const char*)h + (size_t)(f4 * 16);

    float2 sv = ((const float2*)as)[n];
    float es0 = sv.x + adv.x; es0 = es0 >= 0.f ? es0 : NEG_SLOPE * es0;
    float es1 = sv.y + adv.y; es1 = es1 >= 0.f ? es1 : NEG_SLOPE * es1;
    float ps0 = __expf(es0), ps1 = __expf(es1);

    float sum0 = 0.f, sum1 = 0.f;
    float4 acc = make_float4(0.f, 0.f, 0.f, 0.f);

    if (lane < 16) {
        float4 hv = *(const float4*)(hbase + ((size_t)(unsigned)n << 8));
        float pS = headq ? ps1 : ps0;
        acc.x = pS * hv.x; acc.y = pS * hv.y; acc.z = pS * hv.z; acc.w = pS * hv.w;
    }

    for (int base = s0; base < s1; base += 64) {
        int j = base + lane;
        float p0 = 0.f, p1 = 0.f;
        unsigned off = (unsigned)n << 8;
        if (j < s1) {
            int src = col[j];
            float2 av = ((const float2*)as)[src];
            float e0 = av.x + adv.x; e0 = e0 >= 0.f ? e0 : NEG_SLOPE * e0;
            float e1 = av.y + adv.y; e1 = e1 >= 0.f ? e1 : NEG_SLOPE * e1;
            p0 = __expf(e0);
            p1 = __expf(e1);
            sum0 += p0;
            sum1 += p1;
            off = (unsigned)src << 8;
        }
        pbuf[wave][lane] = make_float4(p0, p1, __uint_as_float(off), 0.f);
        int steps = (min(64, s1 - base) + 3) >> 2;
#pragma unroll 4
        for (int i = 0; i < steps; ++i) {
            float4 pv = pbuf[wave][(i << 2) + q];
            float pe = headq ? pv.y : pv.x;
            float4 hv = *(const float4*)(hbase + __float_as_uint(pv.z));
            acc.x = fmaf(pe, hv.x, acc.x);
            acc.y = fmaf(pe, hv.y, acc.y);
            acc.z = fmaf(pe, hv.z, acc.z);
            acc.w = fmaf(pe, hv.w, acc.w);
        }
    }

#pragma unroll
    for (int mk = 32; mk; mk >>= 1) {
        sum0 += __shfl_xor(sum0, mk, 64);
        sum1 += __shfl_xor(sum1, mk, 64);
    }
    sum0 += ps0;
    sum1 += ps1;

    acc.x += __shfl_xor(acc.x, 16, 64); acc.x += __shfl_xor(acc.x, 32, 64);
    acc.y += __shfl_xor(acc.y, 16, 64); acc.y += __shfl_xor(acc.y, 32, 64);
    acc.z += __shfl_xor(acc.z, 16, 64); acc.z += __shfl_xor(acc.z, 32, 64);
    acc.w += __shfl_xor(acc.w, 16, 64); acc.w += __shfl_xor(acc.w, 32, 64);

    if (lane < 16) {
        float inv = 1.f / ((headq ? sum1 : sum0) + 1e-16f);
        float4 bv = ((const float4*)bias)[f4];
        float4 o;
        o.x = fmaf(acc.x, inv, bv.x);
        o.y = fmaf(acc.y, inv, bv.y);
        o.z = fmaf(acc.z, inv, bv.z);
        o.w = fmaf(acc.w, inv, bv.w);
        o.x = o.x > 0.f ? o.x : __expf(o.x) - 1.f;
        o.y = o.y > 0.f ? o.y : __expf(o.y) - 1.f;
        o.z = o.z > 0.f ? o.z : __expf(o.z) - 1.f;
        o.w = o.w > 0.f ? o.w : __expf(o.w) - 1.f;
        ((float4*)(xout + (size_t)n * 64))[f4] = o;
    }
}

// ---------------- fused pooling + MLP head ----------------
// one block per graph; batch is sorted -> binary-search the bounds.
__device__ __forceinline__ int lbound(const int* __restrict__ a, int n, int key) {
    int lo = 0, hi = n;
    while (lo < hi) { int m = (lo + hi) >> 1; if (a[m] < key) lo = m + 1; else hi = m; }
    return lo;
}

__global__ __launch_bounds__(256) void k_head(const float* __restrict__ x,
                                              const int* __restrict__ batch,
                                              const float* __restrict__ w1,
                                              const float* __restrict__ b1,
                                              const float* __restrict__ w2,
                                              const float* __restrict__ b2,
                                              float* __restrict__ out) {
    __shared__ float part[4][64];
    __shared__ float pm[64];
    __shared__ float z[32];
    int g = blockIdx.x, t = threadIdx.x;
    int lane = t & 63, w = t >> 6;
    int lo = lbound(batch, NN, g);
    int hi = lbound(batch, NN, g + 1);
    float acc = 0.f;
    for (int n = lo + w; n < hi; n += 4) acc += x[(size_t)n * 64 + lane];
    part[w][lane] = acc;
    __syncthreads();
    if (t < 64) {
        float s = part[0][t] + part[1][t] + part[2][t] + part[3][t];
        pm[t] = s / (float)max(hi - lo, 1);
    }
    __syncthreads();
    if (t < 32) {
        float a = b1[t];
#pragma unroll
        for (int f = 0; f < 64; ++f) a = fmaf(pm[f], w1[t * 64 + f], a);
        z[t] = fmaxf(a, 0.f);
    }
    __syncthreads();
    if (t < 2) {
        float a = b2[t];
#pragma unroll
        for (int j = 0; j < 32; ++j) a = fmaf(z[j], w2[t * 32 + j], a);
        out[g * 2 + t] = a;
    }
}

extern "C" void kernel_launch(void* const* d_in, const int* in_sizes, int n_in,
                              void* d_out, int out_size, void* d_ws, size_t ws_size,
                              hipStream_t stream) {
    (void)in_sizes; (void)n_in; (void)out_size; (void)ws_size;
    const float* x     = (const float*)d_in[0];
    const int*   ei    = (const int*)d_in[1];
    const int*   batch = (const int*)d_in[2];
    const float* W0    = (const float*)d_in[3];
    const float* aS0   = (const float*)d_in[4];
    const float* aD0   = (const float*)d_in[5];
    const float* b0    = (const float*)d_in[6];
    const float* W1    = (const float*)d_in[7];
    const float* aS1   = (const float*)d_in[8];
    const float* aD1   = (const float*)d_in[9];
    const float* b1    = (const float*)d_in[10];
    const float* W2    = (const float*)d_in[11];
    const float* aS2   = (const float*)d_in[12];
    const float* aD2   = (const float*)d_in[13];
    const float* b2    = (const float*)d_in[14];
    const float* mw1   = (const float*)d_in[15];
    const float* mb1   = (const float*)d_in[16];
    const float* mw2   = (const float*)d_in[17];
    const float* mb2   = (const float*)d_in[18];
    float* out = (float*)d_out;

    char* ws = (char*)d_ws;
    size_t off = 0;
    auto take = [&](size_t bytes) -> char* {
        char* p = ws + off;
        off = (off + bytes + 255) & ~(size_t)255;
        return p;
    };
    int*   gcnt  = (int*)take((size_t)NBUCK * 4);
    int*   rp    = (int*)take((size_t)(NN + 1) * 4);
    int*   col   = (int*)take((size_t)NE * 4);
    float* h     = (float*)take((size_t)NN * 64 * 4);
    float* xbuf  = (float*)take((size_t)NN * 64 * 4);
    float* as_   = (float*)take((size_t)NN * 2 * 4);
    float* ad_   = (float*)take((size_t)NN * 2 * 4);

    // staging for CSR pass A aliases xbuf (16 MB < 25.6 MB; xbuf dead until agg0)
    unsigned* stg = (unsigned*)xbuf;

    hipMemsetAsync(gcnt, 0, (size_t)NBUCK * 4, stream);

    k_binA<<<(NE + 4095) / 4096, 256, 0, stream>>>(ei, gcnt, stg);
    k_binB<<<NBUCK, 256, 0, stream>>>(stg, gcnt, rp, col);

    const int AGG_GRID = (NN + 3) / 4;   // 25000

    // layer 0
    k_gemm<128><<<2048, 256, 0, stream>>>(x, W0, aS0, aD0, h, as_, ad_);
    k_agg<<<AGG_GRID, 256, 0, stream>>>(h, as_, ad_, rp, col, b0, xbuf);
    // layer 1
    k_gemm<64><<<2048, 256, 0, stream>>>(xbuf, W1, aS1, aD1, h, as_, ad_);
    k_agg<<<AGG_GRID, 256, 0, stream>>>(h, as_, ad_, rp, col, b1, xbuf);
    // layer 2
    k_gemm<64><<<2048, 256, 0, stream>>>(xbuf, W2, aS2, aD2, h, as_, ad_);
    k_agg<<<AGG_GRID, 256, 0, stream>>>(h, as_, ad_, rp, col, b2, xbuf);

    // fused pooling + MLP head
    k_head<<<NG, 256, 0, stream>>>(xbuf, batch, mw1, mb1, mw2, mb2, out);
}

// Round 10
// 738.617 us; speedup vs baseline: 1.1818x; 1.1818x over previous
//
#include <hip/hip_runtime.h>
#include <hip/hip_bf16.h>
#include <math.h>

#define NN 100000
#define F_IN 128
#define NHEAD 2
#define NC 32
#define HC 64
#define NE 3200000
#define NG 64
#define NEG_SLOPE 0.2f

#define BSHIFT 8
#define NBUCK ((NN + (1 << BSHIFT) - 1) >> BSHIFT)   // 391
#define BCAP 10240   // mean 8192 edges/bucket, huge headroom

// ---------------- CSR build ----------------
// Pass A: bin edges by dst-bucket into fixed-capacity staging, 4B packed entries.
__global__ __launch_bounds__(256) void k_binA(const int* __restrict__ ei,
                                              int* __restrict__ gcnt,
                                              unsigned* __restrict__ stg) {
    __shared__ int lcnt[NBUCK];
    __shared__ int lbase[NBUCK];
    const int tid = threadIdx.x;
    const int base = blockIdx.x * 4096;
    for (int i = tid; i < NBUCK; i += 256) lcnt[i] = 0;
    __syncthreads();
    unsigned e[16];
    int bk[16], off[16];
#pragma unroll
    for (int i = 0; i < 16; ++i) {
        int j = base + i * 256 + tid;
        bk[i] = -1;
        if (j < NE) {
            unsigned s = (unsigned)ei[j];
            unsigned d = (unsigned)ei[NE + j];
            int b = (int)(d >> BSHIFT);
            bk[i] = b;
            e[i] = ((d & ((1u << BSHIFT) - 1)) << 17) | s;
            off[i] = atomicAdd(&lcnt[b], 1);
        }
    }
    __syncthreads();
    for (int i = tid; i < NBUCK; i += 256) {
        int c = lcnt[i];
        lbase[i] = c ? atomicAdd(&gcnt[i], c) : 0;
    }
    __syncthreads();
#pragma unroll
    for (int i = 0; i < 16; ++i)
        if (bk[i] >= 0)
            stg[(size_t)bk[i] * BCAP + lbase[bk[i]] + off[i]] = e[i];
}

// Pass B: one block per bucket; self-computes its prefix base from gcnt,
// sorts bucket's edges by dst in LDS, emits rp, streams col contiguously.
__global__ __launch_bounds__(256) void k_binB(const unsigned* __restrict__ stg,
                                              const int* __restrict__ gcnt,
                                              int* __restrict__ rp,
                                              int* __restrict__ col) {
    __shared__ int cnt[256];
    __shared__ int off[256];
    __shared__ int buf[BCAP];
    __shared__ int wsum[4];
    const int b = blockIdx.x, t = threadIdx.x;
    const int len = gcnt[b];
    const unsigned* sb = stg + (size_t)b * BCAP;

    int part = 0;
    for (int j = t; j < b; j += 256) part += gcnt[j];
#pragma unroll
    for (int mk = 32; mk; mk >>= 1) part += __shfl_xor(part, mk, 64);
    if ((t & 63) == 0) wsum[t >> 6] = part;
    cnt[t] = 0;
    __syncthreads();
    const int lo = wsum[0] + wsum[1] + wsum[2] + wsum[3];

    for (int j = t; j < len; j += 256) atomicAdd(&cnt[sb[j] >> 17], 1);
    __syncthreads();
    int v = cnt[t];
    off[t] = v;
    __syncthreads();
    for (int d = 1; d < 256; d <<= 1) {
        int u = (t >= d) ? off[t - d] : 0;
        __syncthreads();
        off[t] += u;
        __syncthreads();
    }
    int excl = off[t] - v;
    int node = (b << BSHIFT) + t;
    if (node <= NN) rp[node] = lo + excl;
    __syncthreads();
    off[t] = excl;
    __syncthreads();
    for (int j = t; j < len; j += 256) {
        unsigned e = sb[j];
        int slot = atomicAdd(&off[e >> 17], 1);
        buf[slot] = (int)(e & 0x1FFFFu);
    }
    __syncthreads();
    for (int j = t; j < len; j += 256) col[lo + j] = buf[j];
}

// ---------------- weight transpose: Wt[k][c] = W[c][k] ----------------
__global__ __launch_bounds__(256) void k_wt(const float* __restrict__ W0,
                                            const float* __restrict__ W1,
                                            const float* __restrict__ W2,
                                            float* __restrict__ t0,
                                            float* __restrict__ t1,
                                            float* __restrict__ t2) {
    int idx = blockIdx.x * 256 + threadIdx.x;
    if (idx < 128 * 64) {
        int k = idx >> 6, c = idx & 63;
        t0[idx] = W0[c * 128 + k];
    }
    int i2 = idx - 128 * 64;
    if (i2 >= 0 && i2 < 64 * 64) {
        int k = i2 >> 6, c = i2 & 63;
        t1[i2] = W1[c * 64 + k];
        t2[i2] = W2[c * 64 + k];
    }
}

// ---------------- GEMM + attention-coefficient epilogue ----------------
// lane = output ROW: all 64 output cols accumulate in VGPRs (static-indexed).
// X: per-lane loads, L1 line-reuse across k. W: wave-uniform float4 loads from
// transposed Wt (scalar/L1 broadcast). 64 loads per 256 FMAs -> compute-bound.
// Epilogue alpha dot-products are per-lane (no shuffles at all).
template <int K>
__global__ __launch_bounds__(256) void k_gemm(const float* __restrict__ xin,
                                              const float* __restrict__ Wt,
                                              const float* __restrict__ a_src,
                                              const float* __restrict__ a_dst,
                                              float* __restrict__ h,
                                              float* __restrict__ as_out,
                                              float* __restrict__ ad_out) {
    int n = blockIdx.x * 256 + threadIdx.x;
    if (n >= NN) return;
    const float4* xr = (const float4*)(xin + (size_t)n * K);
    float acc[64];
#pragma unroll
    for (int c = 0; c < 64; ++c) acc[c] = 0.f;

    for (int kq = 0; kq < K / 4; ++kq) {
        float4 xv = xr[kq];
#pragma unroll
        for (int j = 0; j < 4; ++j) {
            float xk = (j == 0) ? xv.x : (j == 1) ? xv.y : (j == 2) ? xv.z : xv.w;
            const float4* wr = (const float4*)(Wt + (size_t)(kq * 4 + j) * 64);
#pragma unroll
            for (int c4 = 0; c4 < 16; ++c4) {
                float4 w = wr[c4];
                acc[c4 * 4 + 0] = fmaf(xk, w.x, acc[c4 * 4 + 0]);
                acc[c4 * 4 + 1] = fmaf(xk, w.y, acc[c4 * 4 + 1]);
                acc[c4 * 4 + 2] = fmaf(xk, w.z, acc[c4 * 4 + 2]);
                acc[c4 * 4 + 3] = fmaf(xk, w.w, acc[c4 * 4 + 3]);
            }
        }
    }

    // h store (lane-owned row, 16x float4)
    float4* hr = (float4*)(h + (size_t)n * 64);
#pragma unroll
    for (int c4 = 0; c4 < 16; ++c4)
        hr[c4] = make_float4(acc[c4 * 4], acc[c4 * 4 + 1], acc[c4 * 4 + 2], acc[c4 * 4 + 3]);

    // per-lane alpha dot products (a_src/a_dst are [2][32] = [64])
    float as0 = 0.f, as1 = 0.f, ad0 = 0.f, ad1 = 0.f;
#pragma unroll
    for (int c = 0; c < 32; ++c) {
        as0 = fmaf(acc[c], a_src[c], as0);
        ad0 = fmaf(acc[c], a_dst[c], ad0);
        as1 = fmaf(acc[32 + c], a_src[32 + c], as1);
        ad1 = fmaf(acc[32 + c], a_dst[32 + c], ad1);
    }
    ((float2*)as_out)[n] = make_float2(as0, as1);
    ((float2*)ad_out)[n] = make_float2(ad0, ad1);
}

// ---------------- per-destination softmax aggregation ----------------
// (unchanged from round 8 — bandwidth-bound at ~117us, clean A/B for gemm)
__global__ __launch_bounds__(256) void k_agg(const float* __restrict__ h,
                                             const float* __restrict__ as,
                                             const float* __restrict__ ad,
                                             const int* __restrict__ rp,
                                             const int* __restrict__ col,
                                             const float* __restrict__ bias,
                                             float* __restrict__ xout) {
    __shared__ float4 pbuf[4][64];
    int wave = threadIdx.x >> 6, lane = threadIdx.x & 63;
    int n = blockIdx.x * 4 + wave;
    if (n >= NN) return;
    int s0 = rp[n], s1 = rp[n + 1];
    float2 adv = ((const float2*)ad)[n];

    int f4 = lane & 15;
    int q = lane >> 4;
    int headq = f4 >> 3;
    const char* hbase = (const char*)h + (size_t)(f4 * 16);

    float2 sv = ((const float2*)as)[n];
    float es0 = sv.x + adv.x; es0 = es0 >= 0.f ? es0 : NEG_SLOPE * es0;
    float es1 = sv.y + adv.y; es1 = es1 >= 0.f ? es1 : NEG_SLOPE * es1;
    float ps0 = __expf(es0), ps1 = __expf(es1);

    float sum0 = 0.f, sum1 = 0.f;
    float4 acc = make_float4(0.f, 0.f, 0.f, 0.f);

    if (lane < 16) {
        float4 hv = *(const float4*)(hbase + ((size_t)(unsigned)n << 8));
        float pS = headq ? ps1 : ps0;
        acc.x = pS * hv.x; acc.y = pS * hv.y; acc.z = pS * hv.z; acc.w = pS * hv.w;
    }

    for (int base = s0; base < s1; base += 64) {
        int j = base + lane;
        float p0 = 0.f, p1 = 0.f;
        unsigned off = (unsigned)n << 8;
        if (j < s1) {
            int src = col[j];
            float2 av = ((const float2*)as)[src];
            float e0 = av.x + adv.x; e0 = e0 >= 0.f ? e0 : NEG_SLOPE * e0;
            float e1 = av.y + adv.y; e1 = e1 >= 0.f ? e1 : NEG_SLOPE * e1;
            p0 = __expf(e0);
            p1 = __expf(e1);
            sum0 += p0;
            sum1 += p1;
            off = (unsigned)src << 8;
        }
        pbuf[wave][lane] = make_float4(p0, p1, __uint_as_float(off), 0.f);
        int steps = (min(64, s1 - base) + 3) >> 2;
#pragma unroll 4
        for (int i = 0; i < steps; ++i) {
            float4 pv = pbuf[wave][(i << 2) + q];
            float pe = headq ? pv.y : pv.x;
            float4 hv = *(const float4*)(hbase + __float_as_uint(pv.z));
            acc.x = fmaf(pe, hv.x, acc.x);
            acc.y = fmaf(pe, hv.y, acc.y);
            acc.z = fmaf(pe, hv.z, acc.z);
            acc.w = fmaf(pe, hv.w, acc.w);
        }
    }

#pragma unroll
    for (int mk = 32; mk; mk >>= 1) {
        sum0 += __shfl_xor(sum0, mk, 64);
        sum1 += __shfl_xor(sum1, mk, 64);
    }
    sum0 += ps0;
    sum1 += ps1;

    acc.x += __shfl_xor(acc.x, 16, 64); acc.x += __shfl_xor(acc.x, 32, 64);
    acc.y += __shfl_xor(acc.y, 16, 64); acc.y += __shfl_xor(acc.y, 32, 64);
    acc.z += __shfl_xor(acc.z, 16, 64); acc.z += __shfl_xor(acc.z, 32, 64);
    acc.w += __shfl_xor(acc.w, 16, 64); acc.w += __shfl_xor(acc.w, 32, 64);

    if (lane < 16) {
        float inv = 1.f / ((headq ? sum1 : sum0) + 1e-16f);
        float4 bv = ((const float4*)bias)[f4];
        float4 o;
        o.x = fmaf(acc.x, inv, bv.x);
        o.y = fmaf(acc.y, inv, bv.y);
        o.z = fmaf(acc.z, inv, bv.z);
        o.w = fmaf(acc.w, inv, bv.w);
        o.x = o.x > 0.f ? o.x : __expf(o.x) - 1.f;
        o.y = o.y > 0.f ? o.y : __expf(o.y) - 1.f;
        o.z = o.z > 0.f ? o.z : __expf(o.z) - 1.f;
        o.w = o.w > 0.f ? o.w : __expf(o.w) - 1.f;
        ((float4*)(xout + (size_t)n * 64))[f4] = o;
    }
}

// ---------------- fused pooling + MLP head ----------------
__device__ __forceinline__ int lbound(const int* __restrict__ a, int n, int key) {
    int lo = 0, hi = n;
    while (lo < hi) { int m = (lo + hi) >> 1; if (a[m] < key) lo = m + 1; else hi = m; }
    return lo;
}

__global__ __launch_bounds__(256) void k_head(const float* __restrict__ x,
                                              const int* __restrict__ batch,
                                              const float* __restrict__ w1,
                                              const float* __restrict__ b1,
                                              const float* __restrict__ w2,
                                              const float* __restrict__ b2,
                                              float* __restrict__ out) {
    __shared__ float part[4][64];
    __shared__ float pm[64];
    __shared__ float z[32];
    int g = blockIdx.x, t = threadIdx.x;
    int lane = t & 63, w = t >> 6;
    int lo = lbound(batch, NN, g);
    int hi = lbound(batch, NN, g + 1);
    float acc = 0.f;
    for (int n = lo + w; n < hi; n += 4) acc += x[(size_t)n * 64 + lane];
    part[w][lane] = acc;
    __syncthreads();
    if (t < 64) {
        float s = part[0][t] + part[1][t] + part[2][t] + part[3][t];
        pm[t] = s / (float)max(hi - lo, 1);
    }
    __syncthreads();
    if (t < 32) {
        float a = b1[t];
#pragma unroll
        for (int f = 0; f < 64; ++f) a = fmaf(pm[f], w1[t * 64 + f], a);
        z[t] = fmaxf(a, 0.f);
    }
    __syncthreads();
    if (t < 2) {
        float a = b2[t];
#pragma unroll
        for (int j = 0; j < 32; ++j) a = fmaf(z[j], w2[t * 32 + j], a);
        out[g * 2 + t] = a;
    }
}

extern "C" void kernel_launch(void* const* d_in, const int* in_sizes, int n_in,
                              void* d_out, int out_size, void* d_ws, size_t ws_size,
                              hipStream_t stream) {
    (void)in_sizes; (void)n_in; (void)out_size; (void)ws_size;
    const float* x     = (const float*)d_in[0];
    const int*   ei    = (const int*)d_in[1];
    const int*   batch = (const int*)d_in[2];
    const float* W0    = (const float*)d_in[3];
    const float* aS0   = (const float*)d_in[4];
    const float* aD0   = (const float*)d_in[5];
    const float* b0    = (const float*)d_in[6];
    const float* W1    = (const float*)d_in[7];
    const float* aS1   = (const float*)d_in[8];
    const float* aD1   = (const float*)d_in[9];
    const float* b1    = (const float*)d_in[10];
    const float* W2    = (const float*)d_in[11];
    const float* aS2   = (const float*)d_in[12];
    const float* aD2   = (const float*)d_in[13];
    const float* b2    = (const float*)d_in[14];
    const float* mw1   = (const float*)d_in[15];
    const float* mb1   = (const float*)d_in[16];
    const float* mw2   = (const float*)d_in[17];
    const float* mb2   = (const float*)d_in[18];
    float* out = (float*)d_out;

    char* ws = (char*)d_ws;
    size_t off = 0;
    auto take = [&](size_t bytes) -> char* {
        char* p = ws + off;
        off = (off + bytes + 255) & ~(size_t)255;
        return p;
    };
    int*   gcnt  = (int*)take((size_t)NBUCK * 4);
    int*   rp    = (int*)take((size_t)(NN + 1) * 4);
    int*   col   = (int*)take((size_t)NE * 4);
    float* h     = (float*)take((size_t)NN * 64 * 4);
    float* xbuf  = (float*)take((size_t)NN * 64 * 4);
    float* as_   = (float*)take((size_t)NN * 2 * 4);
    float* ad_   = (float*)take((size_t)NN * 2 * 4);
    float* wt0   = (float*)take((size_t)128 * 64 * 4);
    float* wt1   = (float*)take((size_t)64 * 64 * 4);
    float* wt2   = (float*)take((size_t)64 * 64 * 4);

    // staging for CSR pass A aliases xbuf (16 MB < 25.6 MB; xbuf dead until agg0)
    unsigned* stg = (unsigned*)xbuf;

    hipMemsetAsync(gcnt, 0, (size_t)NBUCK * 4, stream);

    k_wt<<<48, 256, 0, stream>>>(W0, W1, W2, wt0, wt1, wt2);
    k_binA<<<(NE + 4095) / 4096, 256, 0, stream>>>(ei, gcnt, stg);
    k_binB<<<NBUCK, 256, 0, stream>>>(stg, gcnt, rp, col);

    const int AGG_GRID = (NN + 3) / 4;     // 25000
    const int GEMM_GRID = (NN + 255) / 256; // 391

    // layer 0
    k_gemm<128><<<GEMM_GRID, 256, 0, stream>>>(x, wt0, aS0, aD0, h, as_, ad_);
    k_agg<<<AGG_GRID, 256, 0, stream>>>(h, as_, ad_, rp, col, b0, xbuf);
    // layer 1
    k_gemm<64><<<GEMM_GRID, 256, 0, stream>>>(xbuf, wt1, aS1, aD1, h, as_, ad_);
    k_agg<<<AGG_GRID, 256, 0, stream>>>(h, as_, ad_, rp, col, b1, xbuf);
    // layer 2
    k_gemm<64><<<GEMM_GRID, 256, 0, stream>>>(xbuf, wt2, aS2, aD2, h, as_, ad_);
    k_agg<<<AGG_GRID, 256, 0, stream>>>(h, as_, ad_, rp, col, b2, xbuf);

    // fused pooling + MLP head
    k_head<<<NG, 256, 0, stream>>>(xbuf, batch, mw1, mb1, mw2, mb2, out);
}